// Round 9
// baseline (21.192 us; speedup 1.0000x reference)
//
#include <hip/hip_runtime.h>
#include <hip/hip_bf16.h>

using bf16x8 = __attribute__((ext_vector_type(8))) short;
using f32x4  = __attribute__((ext_vector_type(4))) float;
using f32x16 = __attribute__((ext_vector_type(16))) float;

static constexpr int kN          = 100000;
static constexpr int kFIN        = 128;
static constexpr int kTermStride = 192 * 64;     // W term stride in floats
static constexpr int kTiles32    = kN / 32;      // 3125, exact
static constexpr int kBlocks     = 512;          // 2 per CU, 4096 waves

// round-to-nearest-even f32 -> bf16 (pack path)
__device__ __forceinline__ short f2bf(float v) {
    union { float f; unsigned u; } a; a.f = v;
    unsigned r = a.u + 0x7fffu + ((a.u >> 16) & 1u);
    return (short)(r >> 16);
}

// hot-path packed convert: 2 f32 -> 2 bf16 in one instr (RNE; dst.lo = src0)
__device__ __forceinline__ unsigned cvt_pk_bf16(float a, float b) {
    unsigned r;
    asm("v_cvt_pk_bf16_f32 %0, %1, %2" : "=v"(r) : "v"(a), "v"(b));
    return r;
}

// Fast activations: v_exp_f32 / v_rcp_f32 (~1e-7 rel err, << bf16 noise).
__device__ __forceinline__ float rcp_fast(float x) { return __builtin_amdgcn_rcpf(x); }
__device__ __forceinline__ float sigmoid_fast(float x) {
    return rcp_fast(1.0f + __expf(-x));
}
__device__ __forceinline__ float tanh_fast(float x) {
    float e = __expf(2.0f * x);          // overflow->inf->rcp->0 => tanh=1
    return 1.0f - 2.0f * rcp_fast(e + 1.0f);
}

// sum over each 16-lane row via DPP row_ror (VALU only, no LDS)
__device__ __forceinline__ float row16_sum(float v) {
    int x;
    x = __builtin_amdgcn_update_dpp(0, __float_as_int(v), 0x128, 0xF, 0xF, false);
    v += __int_as_float(x);   // ror:8
    x = __builtin_amdgcn_update_dpp(0, __float_as_int(v), 0x124, 0xF, 0xF, false);
    v += __int_as_float(x);   // ror:4
    x = __builtin_amdgcn_update_dpp(0, __float_as_int(v), 0x122, 0xF, 0xF, false);
    v += __int_as_float(x);   // ror:2
    x = __builtin_amdgcn_update_dpp(0, __float_as_int(v), 0x121, 0xF, 0xF, false);
    v += __int_as_float(x);   // ror:1
    return v;
}

// One fused kernel, 32x32x16 MFMA, one 32-node tile per wave (perfect
// balance: 3125 tiles, 4096 waves, 3125 active).
//
// Pack layout, element (mat,k,c), kap=k>>4, hi=(k>>3)&1, e=k&7,
// jt=c>>5, cl=c&31:
//   idx = mat*8192 + kap*1024 + jt*512 + hi*256 + cl*8 + e   (32 KB)
// Write (512 threads, it=0..3, i=0..3): fidx=it*2048+t*4+i, s=t>>4:
//   k=it*32+s, c=(t&15)*4+i -> kap=it*2+(s>>4), hi=(s>>3)&1, e=s&7,
//   jt=(t&15)>>3, cl=(t&7)*4+i.
// Read fragment (mat,kap,jt), lane l: 8 contiguous shorts at
//   mat*8192 + kap*1024 + jt*512 + (l>>5)*256 + (l&31)*8   (b128, 2-way ok)
// A fragment (32x32x16): lane l holds x[node0+(l&31), kap*16+(l>>5)*8+e].
// C layout (verified): node=(reg&3)+8*(reg>>2)+4*(lane>>5), ch=jt*32+(lane&31).
__global__ __launch_bounds__(512, 4) void fused_gcn(
    const float* __restrict__ x,
    const float* __restrict__ Wz,
    const float* __restrict__ bz,
    const float* __restrict__ Wh,
    const float* __restrict__ bh,
    const float* __restrict__ wlin,
    const float* __restrict__ blin,
    float* __restrict__ out)
{
    __shared__ short lw[16384];   // 32 KB packed weights

    const int t    = threadIdx.x;
    const int wid  = t >> 6;
    const int lane = t & 63;
    const int r32  = lane & 31;   // A row within tile / C channel low bits
    const int hi   = lane >> 5;   // k-half
    const int gw   = blockIdx.x * 8 + wid;
    const bool active = gw < kTiles32;

    // ---- x loads: 16 dwordx4, all in flight during the pack ----
    f32x4 f[16];
    if (active) {
        const float* xrow = x + (size_t)(gw * 32 + r32) * kFIN;
        #pragma unroll
        for (int k2 = 0; k2 < 8; ++k2) {
            f[k2 * 2]     = *(const f32x4*)(xrow + k2 * 16 + hi * 8);
            f[k2 * 2 + 1] = *(const f32x4*)(xrow + k2 * 16 + hi * 8 + 4);
        }
    }

    // Hoisted per-lane epilogue constants (channel = jt*32 + r32)
    float bzc[2], bhc[2], wlc[2];
    #pragma unroll
    for (int jt = 0; jt < 2; ++jt) {
        int c = jt * 32 + r32;
        bzc[jt] = bz[c]; bhc[jt] = bh[c]; wlc[jt] = wlin[c];
    }
    const float bl = blin[0];

    // ---- pack W_sum into LDS (all 512 threads; off critical path) ----
    {
        const int s    = t >> 4;                       // 0..31
        const int jtw  = (t & 15) >> 3;
        const int base = ((s >> 3) & 1) * 256 + ((t & 7) * 4) * 8 + (s & 7)
                       + jtw * 512;
        #pragma unroll
        for (int mat = 0; mat < 2; ++mat) {
            const float* W = mat ? Wh : Wz;
            #pragma unroll
            for (int it = 0; it < 4; ++it) {
                const int fidx = it * 2048 + t * 4;
                f32x4 w0 = *(const f32x4*)(W + fidx);
                f32x4 w1 = *(const f32x4*)(W + kTermStride + fidx);
                const int kap = it * 2 + (s >> 4);
                const int d0  = mat * 8192 + kap * 1024 + base;
                #pragma unroll
                for (int i = 0; i < 4; ++i)
                    lw[d0 + i * 8] = f2bf(w0[i] + w1[i]);
            }
        }
    }
    __syncthreads();
    if (!active) return;

    // ---- cvt x -> bf16 A fragments ----
    bf16x8 a[8];
    #pragma unroll
    for (int k2 = 0; k2 < 8; ++k2) {
        union { unsigned u[4]; bf16x8 v; } p;
        p.u[0] = cvt_pk_bf16(f[k2 * 2][0], f[k2 * 2][1]);
        p.u[1] = cvt_pk_bf16(f[k2 * 2][2], f[k2 * 2][3]);
        p.u[2] = cvt_pk_bf16(f[k2 * 2 + 1][0], f[k2 * 2 + 1][1]);
        p.u[3] = cvt_pk_bf16(f[k2 * 2 + 1][2], f[k2 * 2 + 1][3]);
        a[k2] = p.v;
    }

    // ---- MFMA: [32x128]x[128x64] for z and h ----
    f32x16 accz0, accz1, acch0, acch1;
    #pragma unroll
    for (int q = 0; q < 16; ++q) {
        accz0[q] = 0.f; accz1[q] = 0.f; acch0[q] = 0.f; acch1[q] = 0.f;
    }
    const int rdbase = hi * 256 + r32 * 8;
    #pragma unroll
    for (int k2 = 0; k2 < 8; ++k2) {
        const short* pz = &lw[k2 * 1024 + rdbase];
        bf16x8 wz0 = *(const bf16x8*)(pz);
        bf16x8 wz1 = *(const bf16x8*)(pz + 512);
        bf16x8 wh0 = *(const bf16x8*)(pz + 8192);
        bf16x8 wh1 = *(const bf16x8*)(pz + 8704);
        accz0 = __builtin_amdgcn_mfma_f32_32x32x16_bf16(a[k2], wz0, accz0, 0, 0, 0);
        accz1 = __builtin_amdgcn_mfma_f32_32x32x16_bf16(a[k2], wz1, accz1, 0, 0, 0);
        acch0 = __builtin_amdgcn_mfma_f32_32x32x16_bf16(a[k2], wh0, acch0, 0, 0, 0);
        acch1 = __builtin_amdgcn_mfma_f32_32x32x16_bf16(a[k2], wh1, acch1, 0, 0, 0);
    }

    // ---- epilogue: GRU + relu + Wlin dot, reduce over 32 channel-lanes ----
    float contrib[16];
    #pragma unroll
    for (int j = 0; j < 16; ++j) {
        float z0 = sigmoid_fast(accz0[j] + bzc[0]);
        float h0 = tanh_fast(acch0[j] + bhc[0]);
        float v  = fmaxf((1.0f - z0) * h0, 0.f) * wlc[0];
        float z1 = sigmoid_fast(accz1[j] + bzc[1]);
        float h1 = tanh_fast(acch1[j] + bhc[1]);
        v       += fmaxf((1.0f - z1) * h1, 0.f) * wlc[1];
        contrib[j] = v;
    }
    #pragma unroll
    for (int j = 0; j < 16; ++j) {
        contrib[j] = row16_sum(contrib[j]);
        contrib[j] += __shfl_xor(contrib[j], 16, 64);
    }
    if (r32 == 0) {
        // node = (j&3) + 8*(j>>2) + 4*hi; store 4 contiguous per quad
        #pragma unroll
        for (int b = 0; b < 4; ++b) {
            f32x4 o;
            #pragma unroll
            for (int q = 0; q < 4; ++q) o[q] = contrib[b * 4 + q] + bl;
            *(f32x4*)(out + gw * 32 + b * 8 + hi * 4) = o;
        }
    }
}

extern "C" void kernel_launch(void* const* d_in, const int* in_sizes, int n_in,
                              void* d_out, int out_size, void* d_ws, size_t ws_size,
                              hipStream_t stream) {
    const float* x    = (const float*)d_in[0];
    // d_in[1] edge_index, d_in[2] edge_weight: dead code in reference (K=1, H0=0)
    const float* Wz   = (const float*)d_in[3];
    const float* bz   = (const float*)d_in[4];
    // d_in[5] Wr, d_in[6] br: dead (R*H0 == 0)
    const float* Wh   = (const float*)d_in[7];
    const float* bh   = (const float*)d_in[8];
    const float* wlin = (const float*)d_in[9];
    const float* blin = (const float*)d_in[10];

    fused_gcn<<<dim3(kBlocks), dim3(512), 0, stream>>>(
        x, Wz, bz, Wh, bh, wlin, blin, (float*)d_out);
}

// Round 10
// 17.314 us; speedup vs baseline: 1.2240x; 1.2240x over previous
//
#include <hip/hip_runtime.h>
#include <hip/hip_bf16.h>

using bf16x8 = __attribute__((ext_vector_type(8))) short;
using f32x4  = __attribute__((ext_vector_type(4))) float;

static constexpr int kN          = 100000;
static constexpr int kFIN        = 128;
static constexpr int kTermStride = 192 * 64;     // W term stride in floats
static constexpr int kTiles      = kN / 16;      // 6250, exact
static constexpr int kBlocks     = 512;          // 2 per CU exactly
static constexpr int kWavesTot   = kBlocks * 8;  // 4096
// 2154 extra tiles (6250-4096), spread evenly: waves v=0..3 of every block
// take one (2048), plus wave v=4 of blocks 0..105 (106).

// round-to-nearest-even f32 -> bf16 (pack path)
__device__ __forceinline__ short f2bf(float v) {
    union { float f; unsigned u; } a; a.f = v;
    unsigned r = a.u + 0x7fffu + ((a.u >> 16) & 1u);
    return (short)(r >> 16);
}

// hot-path packed convert: 2 f32 -> 2 bf16 in one instr (RNE; dst.lo = src0)
__device__ __forceinline__ unsigned cvt_pk_bf16(float a, float b) {
    unsigned r;
    asm("v_cvt_pk_bf16_f32 %0, %1, %2" : "=v"(r) : "v"(a), "v"(b));
    return r;
}

// Fast activations: v_exp_f32 / v_rcp_f32 (~1e-7 rel err, << bf16 noise).
__device__ __forceinline__ float rcp_fast(float x) { return __builtin_amdgcn_rcpf(x); }
__device__ __forceinline__ float sigmoid_fast(float x) {
    return rcp_fast(1.0f + __expf(-x));
}
__device__ __forceinline__ float tanh_fast(float x) {
    float e = __expf(2.0f * x);          // overflow->inf->rcp->0 => tanh=1
    return 1.0f - 2.0f * rcp_fast(e + 1.0f);
}

// sum over each 16-lane row via DPP row_ror (VALU only, no LDS)
__device__ __forceinline__ float row16_sum(float v) {
    int x;
    x = __builtin_amdgcn_update_dpp(0, __float_as_int(v), 0x128, 0xF, 0xF, false);
    v += __int_as_float(x);   // ror:8
    x = __builtin_amdgcn_update_dpp(0, __float_as_int(v), 0x124, 0xF, 0xF, false);
    v += __int_as_float(x);   // ror:4
    x = __builtin_amdgcn_update_dpp(0, __float_as_int(v), 0x122, 0xF, 0xF, false);
    v += __int_as_float(x);   // ror:2
    x = __builtin_amdgcn_update_dpp(0, __float_as_int(v), 0x121, 0xF, 0xF, false);
    v += __int_as_float(x);   // ror:1
    return v;
}

// One fused kernel, 512-thread blocks (8 waves), 2 blocks/CU => 4 waves/SIMD.
// Identical to the 18.9us R8 kernel except the second-tile assignment is
// block-interleaved so every CU carries ~ the average node count.
//
// LDS layout, element (mat,k,c), kk=k>>5, g=(k>>3)&3, e=k&7, jt=c>>4, cl=c&15:
//   idx' = mat*8192 + kk*2048 + jt*512 + g*128 + ((cl^jt)<<3) + e
// Write (512 threads, it=0..3): fidx = it*2048 + t*4 + i =>
//   kk=it, s=t>>4, g=s>>3, e=s&7, jt=(t>>2)&3, cl=(t&3)*4+i.
// Read: lane ln uses 16B block (ln^jt) => b128 block-permutation,
// conflict-free.
__global__ __launch_bounds__(512, 4) void fused_gcn(
    const float* __restrict__ x,
    const float* __restrict__ Wz,
    const float* __restrict__ bz,
    const float* __restrict__ Wh,
    const float* __restrict__ bh,
    const float* __restrict__ wlin,
    const float* __restrict__ blin,
    float* __restrict__ out)
{
    __shared__ short lw[16384];   // 32 KB packed weights

    const int t    = threadIdx.x;
    const int wid  = t >> 6;      // wave v within block, 0..7
    const int lane = t & 63;
    const int r    = lane & 15;   // A row within tile / C channel low bits
    const int g    = lane >> 4;   // k-group
    const int b    = blockIdx.x;
    const int gw   = b * 8 + wid;
    const int t0   = gw;                                   // 0..4095
    // balanced extra-tile assignment (see header comment)
    int eid = -1;
    if (wid < 4)                 eid = b * 4 + wid;        // 0..2047
    else if (wid == 4 && b < 106) eid = 2048 + b;          // 2048..2153
    const int t1   = (eid >= 0) ? kWavesTot + eid : -1;    // 4096..6249

    f32x4 f[8];
    auto load_x = [&](int tile) {
        const float* xrow = x + (size_t)(tile * 16 + r) * kFIN;
        #pragma unroll
        for (int kk = 0; kk < 4; ++kk) {
            f[kk * 2]     = *(const f32x4*)(xrow + kk * 32 + g * 8);
            f[kk * 2 + 1] = *(const f32x4*)(xrow + kk * 32 + g * 8 + 4);
        }
    };

    load_x(t0);   // t0's HBM loads in flight during the pack

    // Hoisted per-lane epilogue constants
    float bzc[4], bhc[4], wlc[4];
    #pragma unroll
    for (int jt = 0; jt < 4; ++jt) {
        int c = jt * 16 + r;
        bzc[jt] = bz[c]; bhc[jt] = bh[c]; wlc[jt] = wlin[c];
    }
    const float bl = blin[0];

    // ---- conflict-free XOR-swizzled pack (16 elems/thread) ----
    {
        const int s   = t >> 4;           // 0..31
        const int jtp = (t >> 2) & 3;
        const int base_rt = jtp * 512 + (s >> 3) * 128 + (s & 7);
        short* dst[4];
        #pragma unroll
        for (int i = 0; i < 4; ++i) {
            const int cl = (t & 3) * 4 + i;
            dst[i] = &lw[base_rt + ((cl ^ jtp) << 3)];
        }
        #pragma unroll
        for (int mat = 0; mat < 2; ++mat) {
            const float* W = mat ? Wh : Wz;
            #pragma unroll
            for (int it = 0; it < 4; ++it) {
                const int fidx = it * 2048 + t * 4;
                f32x4 w0 = *(const f32x4*)(W + fidx);
                f32x4 w1 = *(const f32x4*)(W + kTermStride + fidx);
                const int cmi = mat * 8192 + it * 2048;   // kk = it
                #pragma unroll
                for (int i = 0; i < 4; ++i)
                    dst[i][cmi] = f2bf(w0[i] + w1[i]);
            }
        }
    }
    __syncthreads();

    // per-jt swizzled read offsets (shorts), reused across kk/mat/tiles
    int lx[4];
    #pragma unroll
    for (int jt = 0; jt < 4; ++jt) lx[jt] = ((lane ^ jt) << 3);

    bf16x8 a[4];
    auto cvt = [&]() {
        #pragma unroll
        for (int kk = 0; kk < 4; ++kk) {
            union { unsigned u[4]; bf16x8 v; } p;
            p.u[0] = cvt_pk_bf16(f[kk * 2][0], f[kk * 2][1]);
            p.u[1] = cvt_pk_bf16(f[kk * 2][2], f[kk * 2][3]);
            p.u[2] = cvt_pk_bf16(f[kk * 2 + 1][0], f[kk * 2 + 1][1]);
            p.u[3] = cvt_pk_bf16(f[kk * 2 + 1][2], f[kk * 2 + 1][3]);
            a[kk] = p.v;
        }
    };

    auto compute_tile = [&](int tile) {
        f32x4 accz[4], acch[4];
        #pragma unroll
        for (int jt = 0; jt < 4; ++jt) {
            accz[jt] = f32x4{0.f, 0.f, 0.f, 0.f};
            acch[jt] = f32x4{0.f, 0.f, 0.f, 0.f};
        }
        #pragma unroll
        for (int kk = 0; kk < 4; ++kk) {
            #pragma unroll
            for (int jt = 0; jt < 4; ++jt) {
                const int off = ((kk * 4 + jt) << 9) + lx[jt];
                bf16x8 wz = *(const bf16x8*)&lw[off];
                bf16x8 wh = *(const bf16x8*)&lw[8192 + off];
                accz[jt] = __builtin_amdgcn_mfma_f32_16x16x32_bf16(a[kk], wz, accz[jt], 0, 0, 0);
                acch[jt] = __builtin_amdgcn_mfma_f32_16x16x32_bf16(a[kk], wh, acch[jt], 0, 0, 0);
            }
        }
        // epilogue: C layout channel = jt*16 + r, node-in-tile = g*4 + reg
        float contrib[4] = {0.f, 0.f, 0.f, 0.f};
        #pragma unroll
        for (int jt = 0; jt < 4; ++jt) {
            #pragma unroll
            for (int i = 0; i < 4; ++i) {
                float z  = sigmoid_fast(accz[jt][i] + bzc[jt]);
                float ht = tanh_fast(acch[jt][i] + bhc[jt]);
                float H  = (1.0f - z) * ht;
                contrib[i] += fmaxf(H, 0.f) * wlc[jt];
            }
        }
        #pragma unroll
        for (int i = 0; i < 4; ++i) contrib[i] = row16_sum(contrib[i]);
        if (r == 0) {
            f32x4 o;
            #pragma unroll
            for (int i = 0; i < 4; ++i) o[i] = contrib[i] + bl;
            *(f32x4*)(out + tile * 16 + g * 4) = o;
        }
    };

    // tile 0 (prefetch tile 1 during its compute)
    cvt();
    if (t1 >= 0) load_x(t1);
    compute_tile(t0);
    // optional tile 1 (balanced across blocks)
    if (t1 >= 0) {
        cvt();
        compute_tile(t1);
    }
}

extern "C" void kernel_launch(void* const* d_in, const int* in_sizes, int n_in,
                              void* d_out, int out_size, void* d_ws, size_t ws_size,
                              hipStream_t stream) {
    const float* x    = (const float*)d_in[0];
    // d_in[1] edge_index, d_in[2] edge_weight: dead code in reference (K=1, H0=0)
    const float* Wz   = (const float*)d_in[3];
    const float* bz   = (const float*)d_in[4];
    // d_in[5] Wr, d_in[6] br: dead (R*H0 == 0)
    const float* Wh   = (const float*)d_in[7];
    const float* bh   = (const float*)d_in[8];
    const float* wlin = (const float*)d_in[9];
    const float* blin = (const float*)d_in[10];

    fused_gcn<<<dim3(kBlocks), dim3(512), 0, stream>>>(
        x, Wz, bz, Wh, bh, wlin, blin, (float*)d_out);
}